// Round 1
// baseline (476.082 us; speedup 1.0000x reference)
//
#include <hip/hip_runtime.h>
#include <hip/hip_bf16.h>

#define N_NODES 50000
#define N_EDGES 800000
#define E_TOT   850000   // + self loops
#define NBLK    256      // nodes per gemm block

// ---------------- CSR build ----------------

__global__ void hist_kernel(const int* __restrict__ ei, int* __restrict__ counts) {
    int e = blockIdx.x * blockDim.x + threadIdx.x;
    if (e >= E_TOT) return;
    int d = (e < N_EDGES) ? ei[N_EDGES + e] : (e - N_EDGES);
    atomicAdd(&counts[d], 1);
}

__global__ __launch_bounds__(1024) void scan_kernel(const int* __restrict__ counts,
                                                    int* __restrict__ offs,
                                                    int* __restrict__ fill) {
    __shared__ int sums[1024];
    const int n = N_NODES, C = 49; // 1024*49 >= 50000
    int t = threadIdx.x;
    int lo = t * C, hi = min(lo + C, n);
    int s = 0;
    for (int i = lo; i < hi; i++) s += counts[i];
    sums[t] = s;
    __syncthreads();
    for (int d = 1; d < 1024; d <<= 1) {
        int v = (t >= d) ? sums[t - d] : 0;
        __syncthreads();
        sums[t] += v;
        __syncthreads();
    }
    int prefix = (t == 0) ? 0 : sums[t - 1];
    for (int i = lo; i < hi; i++) {
        offs[i] = prefix;
        fill[i] = prefix;
        prefix += counts[i];
    }
    if (t == 0) offs[n] = E_TOT;
}

__global__ void scatter_kernel(const int* __restrict__ ei, int* __restrict__ fill,
                               int* __restrict__ bucket) {
    int e = blockIdx.x * blockDim.x + threadIdx.x;
    if (e >= E_TOT) return;
    int s, d;
    if (e < N_EDGES) { s = ei[e]; d = ei[N_EDGES + e]; }
    else             { s = d = e - N_EDGES; }
    int pos = atomicAdd(&fill[d], 1);
    bucket[pos] = s;
}

// deterministic ordering: sort each node's bucket by src id
__global__ void sort_kernel(const int* __restrict__ offs, int* __restrict__ bucket) {
    int v = blockIdx.x * blockDim.x + threadIdx.x;
    if (v >= N_NODES) return;
    int a = offs[v], b = offs[v + 1];
    for (int i = a + 1; i < b; i++) {
        int key = bucket[i];
        int j = i - 1;
        while (j >= a && bucket[j] > key) { bucket[j + 1] = bucket[j]; j--; }
        bucket[j + 1] = key;
    }
}

// ---------------- layer 1 GEMM: h1 = x @ W1, plus per-(node,head) attn dots ----------------
// thread = (head, 4 consecutive nodes); block covers 256 nodes.
__global__ __launch_bounds__(256) void gemm1_kernel(const float* __restrict__ x,
                                                    const float* __restrict__ W1,
                                                    const float* __restrict__ asrc1,
                                                    const float* __restrict__ adst1,
                                                    float* __restrict__ h1,
                                                    float* __restrict__ as1,
                                                    float* __restrict__ ad1) {
    // W layout: wlds[head*4104 + k*32 + j]  (head stride 4104 -> bank offset 8*head)
    __shared__ __align__(16) float wlds[4 * 4104];
    // x tile transposed: xs[kk*260 + row]  (row-stride 260 -> <=2-way conflicts)
    __shared__ __align__(16) float xs[32 * 260];

    const int tid = threadIdx.x;
    const int head = tid & 3;
    const int q = tid >> 2;              // 0..63  -> nodes base+q*4 .. +3
    const int base = blockIdx.x * NBLK;

    for (int idx = tid; idx < 128 * 128; idx += 256) {
        int k = idx >> 7, col = idx & 127;
        wlds[(col >> 5) * 4104 + k * 32 + (col & 31)] = W1[idx];
    }

    float acc[4][32];
#pragma unroll
    for (int i = 0; i < 4; i++)
#pragma unroll
        for (int j = 0; j < 32; j++) acc[i][j] = 0.f;

    for (int kt = 0; kt < 4; kt++) {
        __syncthreads(); // protects xs reuse (and W load on first iter)
#pragma unroll
        for (int it = 0; it < 8; it++) {
            int idx = tid + it * 256;
            int row = idx >> 3, c4 = idx & 7;
            int node = base + row;
            float4 v = make_float4(0.f, 0.f, 0.f, 0.f);
            if (node < N_NODES)
                v = *(const float4*)(x + (size_t)node * 128 + kt * 32 + c4 * 4);
            xs[(c4 * 4 + 0) * 260 + row] = v.x;
            xs[(c4 * 4 + 1) * 260 + row] = v.y;
            xs[(c4 * 4 + 2) * 260 + row] = v.z;
            xs[(c4 * 4 + 3) * 260 + row] = v.w;
        }
        __syncthreads();

        for (int kk = 0; kk < 32; kk++) {
            float4 xv = *(const float4*)(xs + kk * 260 + q * 4);
            const float* wb = wlds + head * 4104 + (kt * 32 + kk) * 32;
            float xvv[4] = {xv.x, xv.y, xv.z, xv.w};
#pragma unroll
            for (int j4 = 0; j4 < 8; j4++) {
                float4 wv = *(const float4*)(wb + j4 * 4);
                float wvv[4] = {wv.x, wv.y, wv.z, wv.w};
#pragma unroll
                for (int i = 0; i < 4; i++)
#pragma unroll
                    for (int c = 0; c < 4; c++)
                        acc[i][j4 * 4 + c] += xvv[i] * wvv[c];
            }
        }
    }

    // epilogue: write h1 and attention half-dots
#pragma unroll
    for (int i = 0; i < 4; i++) {
        int node = base + q * 4 + i;
        if (node >= N_NODES) continue;
#pragma unroll
        for (int j4 = 0; j4 < 8; j4++) {
            float4 hv = make_float4(acc[i][j4 * 4 + 0], acc[i][j4 * 4 + 1],
                                    acc[i][j4 * 4 + 2], acc[i][j4 * 4 + 3]);
            *(float4*)(h1 + (size_t)node * 128 + head * 32 + j4 * 4) = hv;
        }
        float sa = 0.f, da = 0.f;
#pragma unroll
        for (int j = 0; j < 32; j++) {
            float v = acc[i][j];
            sa += v * asrc1[head * 32 + j];
            da += v * adst1[head * 32 + j];
        }
        as1[node * 4 + head] = sa;
        ad1[node * 4 + head] = da;
    }
}

// ---------------- layer 1 aggregation (+bias, ELU, layer-2 projection) ----------------
// one wave per dst node; lane l owns channels 2l, 2l+1 (head = l>>4).
// softmax without max-subtract (logits bounded); denom tracked per-lane.
__global__ __launch_bounds__(256) void agg1_kernel(const float* __restrict__ h1,
                                                   const float* __restrict__ as1,
                                                   const float* __restrict__ ad1,
                                                   const int* __restrict__ offs,
                                                   const int* __restrict__ bucket,
                                                   const float* __restrict__ b1,
                                                   const float* __restrict__ W2,
                                                   float* __restrict__ x2,
                                                   float* __restrict__ h2s) {
    int w = threadIdx.x >> 6, l = threadIdx.x & 63;
    int node = blockIdx.x * 4 + w;
    if (node >= N_NODES) return;
    int head = l >> 4;
    float adh = ad1[node * 4 + head];
    int a = offs[node];
    int deg = offs[node + 1] - a;

    float sx = 0.f, ax = 0.f, ay = 0.f;
    for (int i = 0; i < deg; i++) {
        int s = bucket[a + i];
        float e = as1[s * 4 + head] + adh;
        e = (e > 0.f) ? e : 0.2f * e;
        float ex = __expf(e);
        float2 hv = ((const float2*)(h1 + (size_t)s * 128))[l];
        sx += ex;
        ax += ex * hv.x;
        ay += ex * hv.y;
    }
    float r = 1.f / (sx + 1e-16f);
    float2 bv = ((const float2*)b1)[l];
    float ox = ax * r + bv.x;
    float oy = ay * r + bv.y;
    // ELU
    float xx = (ox > 0.f) ? ox : (__expf(ox) - 1.f);
    float xy = (oy > 0.f) ? oy : (__expf(oy) - 1.f);
    ((float2*)(x2 + (size_t)node * 128))[l] = make_float2(xx, xy);
    // layer-2 linear: h2s[node] = elu(out1) . W2
    float2 wv = ((const float2*)W2)[l];
    float p = xx * wv.x + xy * wv.y;
#pragma unroll
    for (int o = 32; o > 0; o >>= 1) p += __shfl_xor(p, o, 64);
    if (l == 0) h2s[node] = p;
}

// ---------------- layer 2 aggregation ----------------
// one wave per dst node; lanes parallel over edges.
__global__ __launch_bounds__(256) void agg2_kernel(const float* __restrict__ h2s,
                                                   const int* __restrict__ offs,
                                                   const int* __restrict__ bucket,
                                                   const float* __restrict__ asrc2,
                                                   const float* __restrict__ adst2,
                                                   const float* __restrict__ b2,
                                                   float* __restrict__ out) {
    int w = threadIdx.x >> 6, l = threadIdx.x & 63;
    int node = blockIdx.x * 4 + w;
    if (node >= N_NODES) return;
    float asc = asrc2[0], adc = adst2[0], bias = b2[0];
    float adn = h2s[node] * adc;
    int a = offs[node], b = offs[node + 1];
    float sx = 0.f, sw = 0.f;
    for (int i = a + l; i < b; i += 64) {
        float hs = h2s[bucket[i]];
        float e = hs * asc + adn;
        e = (e > 0.f) ? e : 0.2f * e;
        float ex = __expf(e);
        sx += ex;
        sw += ex * hs;
    }
#pragma unroll
    for (int o = 32; o > 0; o >>= 1) {
        sx += __shfl_xor(sx, o, 64);
        sw += __shfl_xor(sw, o, 64);
    }
    if (l == 0) out[node] = sw / (sx + 1e-16f) + bias;
}

// ---------------- launch ----------------

extern "C" void kernel_launch(void* const* d_in, const int* in_sizes, int n_in,
                              void* d_out, int out_size, void* d_ws, size_t ws_size,
                              hipStream_t stream) {
    const float* x     = (const float*)d_in[0];
    const int*   ei    = (const int*)d_in[1];
    const float* W1    = (const float*)d_in[2];
    const float* asrc1 = (const float*)d_in[3];
    const float* adst1 = (const float*)d_in[4];
    const float* b1    = (const float*)d_in[5];
    const float* W2    = (const float*)d_in[6];
    const float* asrc2 = (const float*)d_in[7];
    const float* adst2 = (const float*)d_in[8];
    const float* b2    = (const float*)d_in[9];
    float* out = (float*)d_out;

    char* ws = (char*)d_ws;
    size_t o = 0;
    auto alloc = [&](size_t bytes) -> void* {
        void* p = ws + o;
        o += (bytes + 255) & ~(size_t)255;
        return p;
    };
    int* counts  = (int*)alloc((size_t)N_NODES * 4);
    int* offs    = (int*)alloc((size_t)(N_NODES + 1) * 4);
    int* fill    = (int*)alloc((size_t)N_NODES * 4);
    int* bucket  = (int*)alloc((size_t)E_TOT * 4);
    float* h1    = (float*)alloc((size_t)N_NODES * 128 * 4);
    float* as1   = (float*)alloc((size_t)N_NODES * 4 * 4);
    float* ad1   = (float*)alloc((size_t)N_NODES * 4 * 4);
    float* x2    = (float*)alloc((size_t)N_NODES * 128 * 4);
    float* h2s   = (float*)alloc((size_t)N_NODES * 4);

    hipMemsetAsync(counts, 0, (size_t)N_NODES * 4, stream);

    hist_kernel<<<(E_TOT + 255) / 256, 256, 0, stream>>>(ei, counts);
    scan_kernel<<<1, 1024, 0, stream>>>(counts, offs, fill);
    scatter_kernel<<<(E_TOT + 255) / 256, 256, 0, stream>>>(ei, fill, bucket);
    sort_kernel<<<(N_NODES + 255) / 256, 256, 0, stream>>>(offs, bucket);

    gemm1_kernel<<<(N_NODES + NBLK - 1) / NBLK, 256, 0, stream>>>(
        x, W1, asrc1, adst1, h1, as1, ad1);

    agg1_kernel<<<(N_NODES + 3) / 4, 256, 0, stream>>>(
        h1, as1, ad1, offs, bucket, b1, W2, x2, h2s);

    agg2_kernel<<<(N_NODES + 3) / 4, 256, 0, stream>>>(
        h2s, offs, bucket, asrc2, adst2, b2, out);
}

// Round 2
// 373.815 us; speedup vs baseline: 1.2736x; 1.2736x over previous
//
#include <hip/hip_runtime.h>
#include <hip/hip_bf16.h>

#define N_NODES 50000
#define N_EDGES 800000
#define E_TOT   850000   // + self loops
#define NBLK    256      // nodes per gemm block
#define SCAN_BLOCKS 196  // ceil(50000/256)

// ---------------- CSR build ----------------

__global__ void hist_kernel(const int* __restrict__ ei, int* __restrict__ counts) {
    int e = blockIdx.x * blockDim.x + threadIdx.x;
    if (e >= E_TOT) return;
    int d = (e < N_EDGES) ? ei[N_EDGES + e] : (e - N_EDGES);
    atomicAdd(&counts[d], 1);
}

// hierarchical exclusive scan: local 256-scan -> block-sum scan -> add base
__global__ __launch_bounds__(256) void scan1_kernel(const int* __restrict__ counts,
                                                    int* __restrict__ localScan,
                                                    int* __restrict__ blockSums) {
    __shared__ int tmp[256];
    int t = threadIdx.x, i = blockIdx.x * 256 + t;
    int v = (i < N_NODES) ? counts[i] : 0;
    tmp[t] = v;
    __syncthreads();
    for (int d = 1; d < 256; d <<= 1) {
        int u = (t >= d) ? tmp[t - d] : 0;
        __syncthreads();
        tmp[t] += u;
        __syncthreads();
    }
    if (i < N_NODES) localScan[i] = tmp[t] - v;  // exclusive
    if (t == 255) blockSums[blockIdx.x] = tmp[t];
}

__global__ __launch_bounds__(256) void scan2_kernel(const int* __restrict__ blockSums,
                                                    int* __restrict__ blockBase) {
    __shared__ int tmp[256];
    int t = threadIdx.x;
    int v = (t < SCAN_BLOCKS) ? blockSums[t] : 0;
    tmp[t] = v;
    __syncthreads();
    for (int d = 1; d < 256; d <<= 1) {
        int u = (t >= d) ? tmp[t - d] : 0;
        __syncthreads();
        tmp[t] += u;
        __syncthreads();
    }
    blockBase[t] = tmp[t] - v;  // exclusive
}

__global__ void scan3_kernel(const int* __restrict__ localScan,
                             const int* __restrict__ blockBase,
                             int* __restrict__ offs, int* __restrict__ fill) {
    int i = blockIdx.x * 256 + threadIdx.x;
    if (i < N_NODES) {
        int o = localScan[i] + blockBase[i >> 8];
        offs[i] = o;
        fill[i] = o;
    }
    if (i == 0) offs[N_NODES] = E_TOT;
}

__global__ void scatter_kernel(const int* __restrict__ ei, int* __restrict__ fill,
                               int* __restrict__ bucket) {
    int e = blockIdx.x * blockDim.x + threadIdx.x;
    if (e >= E_TOT) return;
    int s, d;
    if (e < N_EDGES) { s = ei[e]; d = ei[N_EDGES + e]; }
    else             { s = d = e - N_EDGES; }
    int pos = atomicAdd(&fill[d], 1);
    bucket[pos] = s;
}

// deterministic ordering: sort each node's bucket by src id
__global__ void sort_kernel(const int* __restrict__ offs, int* __restrict__ bucket) {
    int v = blockIdx.x * blockDim.x + threadIdx.x;
    if (v >= N_NODES) return;
    int a = offs[v], b = offs[v + 1];
    for (int i = a + 1; i < b; i++) {
        int key = bucket[i];
        int j = i - 1;
        while (j >= a && bucket[j] > key) { bucket[j + 1] = bucket[j]; j--; }
        bucket[j + 1] = key;
    }
}

// ---------------- layer 1 GEMM: h1 = x @ W1, plus per-(node,head) attn dots ----------------
// thread = (head, 4 consecutive nodes); block covers 256 nodes.
__global__ __launch_bounds__(256) void gemm1_kernel(const float* __restrict__ x,
                                                    const float* __restrict__ W1,
                                                    const float* __restrict__ asrc1,
                                                    const float* __restrict__ adst1,
                                                    float* __restrict__ h1,
                                                    float* __restrict__ as1,
                                                    float* __restrict__ ad1) {
    // W layout: wlds[head*4104 + k*32 + j]  (head stride 4104 -> bank offset 8*head)
    __shared__ __align__(16) float wlds[4 * 4104];
    // x tile transposed: xs[kk*260 + row]  (row-stride 260 -> <=2-way conflicts)
    __shared__ __align__(16) float xs[32 * 260];

    const int tid = threadIdx.x;
    const int head = tid & 3;
    const int q = tid >> 2;              // 0..63  -> nodes base+q*4 .. +3
    const int base = blockIdx.x * NBLK;

    for (int idx = tid; idx < 128 * 128; idx += 256) {
        int k = idx >> 7, col = idx & 127;
        wlds[(col >> 5) * 4104 + k * 32 + (col & 31)] = W1[idx];
    }

    float acc[4][32];
#pragma unroll
    for (int i = 0; i < 4; i++)
#pragma unroll
        for (int j = 0; j < 32; j++) acc[i][j] = 0.f;

    for (int kt = 0; kt < 4; kt++) {
        __syncthreads(); // protects xs reuse (and W load on first iter)
#pragma unroll
        for (int it = 0; it < 8; it++) {
            int idx = tid + it * 256;
            int row = idx >> 3, c4 = idx & 7;
            int node = base + row;
            float4 v = make_float4(0.f, 0.f, 0.f, 0.f);
            if (node < N_NODES)
                v = *(const float4*)(x + (size_t)node * 128 + kt * 32 + c4 * 4);
            xs[(c4 * 4 + 0) * 260 + row] = v.x;
            xs[(c4 * 4 + 1) * 260 + row] = v.y;
            xs[(c4 * 4 + 2) * 260 + row] = v.z;
            xs[(c4 * 4 + 3) * 260 + row] = v.w;
        }
        __syncthreads();

        for (int kk = 0; kk < 32; kk++) {
            float4 xv = *(const float4*)(xs + kk * 260 + q * 4);
            const float* wb = wlds + head * 4104 + (kt * 32 + kk) * 32;
            float xvv[4] = {xv.x, xv.y, xv.z, xv.w};
#pragma unroll
            for (int j4 = 0; j4 < 8; j4++) {
                float4 wv = *(const float4*)(wb + j4 * 4);
                float wvv[4] = {wv.x, wv.y, wv.z, wv.w};
#pragma unroll
                for (int i = 0; i < 4; i++)
#pragma unroll
                    for (int c = 0; c < 4; c++)
                        acc[i][j4 * 4 + c] += xvv[i] * wvv[c];
            }
        }
    }

    // epilogue: write h1 and attention half-dots
#pragma unroll
    for (int i = 0; i < 4; i++) {
        int node = base + q * 4 + i;
        if (node >= N_NODES) continue;
#pragma unroll
        for (int j4 = 0; j4 < 8; j4++) {
            float4 hv = make_float4(acc[i][j4 * 4 + 0], acc[i][j4 * 4 + 1],
                                    acc[i][j4 * 4 + 2], acc[i][j4 * 4 + 3]);
            *(float4*)(h1 + (size_t)node * 128 + head * 32 + j4 * 4) = hv;
        }
        float sa = 0.f, da = 0.f;
#pragma unroll
        for (int j = 0; j < 32; j++) {
            float v = acc[i][j];
            sa += v * asrc1[head * 32 + j];
            da += v * adst1[head * 32 + j];
        }
        as1[node * 4 + head] = sa;
        ad1[node * 4 + head] = da;
    }
}

// ---------------- layer 1 aggregation (+bias, ELU, layer-2 projection) ----------------
// one wave per dst node; lane l owns channels 2l, 2l+1 (head = l>>4).
// softmax without max-subtract (logits bounded); denom tracked per-lane.
__global__ __launch_bounds__(256) void agg1_kernel(const float* __restrict__ h1,
                                                   const float* __restrict__ as1,
                                                   const float* __restrict__ ad1,
                                                   const int* __restrict__ offs,
                                                   const int* __restrict__ bucket,
                                                   const float* __restrict__ b1,
                                                   const float* __restrict__ W2,
                                                   float* __restrict__ x2,
                                                   float* __restrict__ h2s) {
    int w = threadIdx.x >> 6, l = threadIdx.x & 63;
    int node = blockIdx.x * 4 + w;
    if (node >= N_NODES) return;
    int head = l >> 4;
    float adh = ad1[node * 4 + head];
    int a = offs[node];
    int deg = offs[node + 1] - a;

    float sx = 0.f, ax = 0.f, ay = 0.f;
    for (int i = 0; i < deg; i++) {
        int s = bucket[a + i];
        float e = as1[s * 4 + head] + adh;
        e = (e > 0.f) ? e : 0.2f * e;
        float ex = __expf(e);
        float2 hv = ((const float2*)(h1 + (size_t)s * 128))[l];
        sx += ex;
        ax += ex * hv.x;
        ay += ex * hv.y;
    }
    float r = 1.f / (sx + 1e-16f);
    float2 bv = ((const float2*)b1)[l];
    float ox = ax * r + bv.x;
    float oy = ay * r + bv.y;
    // ELU
    float xx = (ox > 0.f) ? ox : (__expf(ox) - 1.f);
    float xy = (oy > 0.f) ? oy : (__expf(oy) - 1.f);
    ((float2*)(x2 + (size_t)node * 128))[l] = make_float2(xx, xy);
    // layer-2 linear: h2s[node] = elu(out1) . W2
    float2 wv = ((const float2*)W2)[l];
    float p = xx * wv.x + xy * wv.y;
#pragma unroll
    for (int o = 32; o > 0; o >>= 1) p += __shfl_xor(p, o, 64);
    if (l == 0) h2s[node] = p;
}

// ---------------- layer 2 aggregation ----------------
// one wave per dst node; lanes parallel over edges.
__global__ __launch_bounds__(256) void agg2_kernel(const float* __restrict__ h2s,
                                                   const int* __restrict__ offs,
                                                   const int* __restrict__ bucket,
                                                   const float* __restrict__ asrc2,
                                                   const float* __restrict__ adst2,
                                                   const float* __restrict__ b2,
                                                   float* __restrict__ out) {
    int w = threadIdx.x >> 6, l = threadIdx.x & 63;
    int node = blockIdx.x * 4 + w;
    if (node >= N_NODES) return;
    float asc = asrc2[0], adc = adst2[0], bias = b2[0];
    float adn = h2s[node] * adc;
    int a = offs[node], b = offs[node + 1];
    float sx = 0.f, sw = 0.f;
    for (int i = a + l; i < b; i += 64) {
        float hs = h2s[bucket[i]];
        float e = hs * asc + adn;
        e = (e > 0.f) ? e : 0.2f * e;
        float ex = __expf(e);
        sx += ex;
        sw += ex * hs;
    }
#pragma unroll
    for (int o = 32; o > 0; o >>= 1) {
        sx += __shfl_xor(sx, o, 64);
        sw += __shfl_xor(sw, o, 64);
    }
    if (l == 0) out[node] = sw / (sx + 1e-16f) + bias;
}

// ---------------- launch ----------------

extern "C" void kernel_launch(void* const* d_in, const int* in_sizes, int n_in,
                              void* d_out, int out_size, void* d_ws, size_t ws_size,
                              hipStream_t stream) {
    const float* x     = (const float*)d_in[0];
    const int*   ei    = (const int*)d_in[1];
    const float* W1    = (const float*)d_in[2];
    const float* asrc1 = (const float*)d_in[3];
    const float* adst1 = (const float*)d_in[4];
    const float* b1    = (const float*)d_in[5];
    const float* W2    = (const float*)d_in[6];
    const float* asrc2 = (const float*)d_in[7];
    const float* adst2 = (const float*)d_in[8];
    const float* b2    = (const float*)d_in[9];
    float* out = (float*)d_out;

    char* ws = (char*)d_ws;
    size_t o = 0;
    auto alloc = [&](size_t bytes) -> void* {
        void* p = ws + o;
        o += (bytes + 255) & ~(size_t)255;
        return p;
    };
    int* counts  = (int*)alloc((size_t)N_NODES * 4);
    int* offs    = (int*)alloc((size_t)(N_NODES + 1) * 4);
    int* fill    = (int*)alloc((size_t)N_NODES * 4);
    int* bucket  = (int*)alloc((size_t)E_TOT * 4);
    float* h1    = (float*)alloc((size_t)N_NODES * 128 * 4);
    float* as1   = (float*)alloc((size_t)N_NODES * 4 * 4);
    float* ad1   = (float*)alloc((size_t)N_NODES * 4 * 4);
    float* x2    = (float*)alloc((size_t)N_NODES * 128 * 4);
    float* h2s   = (float*)alloc((size_t)N_NODES * 4);
    int* localScan = (int*)alloc((size_t)N_NODES * 4);
    int* blockSums = (int*)alloc((size_t)SCAN_BLOCKS * 4);
    int* blockBase = (int*)alloc((size_t)256 * 4);

    hipMemsetAsync(counts, 0, (size_t)N_NODES * 4, stream);

    hist_kernel<<<(E_TOT + 255) / 256, 256, 0, stream>>>(ei, counts);
    scan1_kernel<<<SCAN_BLOCKS, 256, 0, stream>>>(counts, localScan, blockSums);
    scan2_kernel<<<1, 256, 0, stream>>>(blockSums, blockBase);
    scan3_kernel<<<SCAN_BLOCKS, 256, 0, stream>>>(localScan, blockBase, offs, fill);
    scatter_kernel<<<(E_TOT + 255) / 256, 256, 0, stream>>>(ei, fill, bucket);
    sort_kernel<<<(N_NODES + 255) / 256, 256, 0, stream>>>(offs, bucket);

    gemm1_kernel<<<(N_NODES + NBLK - 1) / NBLK, 256, 0, stream>>>(
        x, W1, asrc1, adst1, h1, as1, ad1);

    agg1_kernel<<<(N_NODES + 3) / 4, 256, 0, stream>>>(
        h1, as1, ad1, offs, bucket, b1, W2, x2, h2s);

    agg2_kernel<<<(N_NODES + 3) / 4, 256, 0, stream>>>(
        h2s, offs, bucket, asrc2, adst2, b2, out);
}

// Round 3
// 296.232 us; speedup vs baseline: 1.6071x; 1.2619x over previous
//
#include <hip/hip_runtime.h>
#include <hip/hip_bf16.h>

#define N_NODES 50000
#define N_EDGES 800000
#define E_TOT   850000   // + self loops
#define NBLK    256      // nodes per gemm block
#define SCAN_BLOCKS 196  // ceil(50000/256)

// ---------------- CSR build ----------------

__global__ void hist_kernel(const int* __restrict__ ei, int* __restrict__ counts) {
    int e = blockIdx.x * blockDim.x + threadIdx.x;
    if (e >= E_TOT) return;
    int d = (e < N_EDGES) ? ei[N_EDGES + e] : (e - N_EDGES);
    atomicAdd(&counts[d], 1);
}

// hierarchical exclusive scan: local 256-scan -> block-sum scan -> add base
__global__ __launch_bounds__(256) void scan1_kernel(const int* __restrict__ counts,
                                                    int* __restrict__ localScan,
                                                    int* __restrict__ blockSums) {
    __shared__ int tmp[256];
    int t = threadIdx.x, i = blockIdx.x * 256 + t;
    int v = (i < N_NODES) ? counts[i] : 0;
    tmp[t] = v;
    __syncthreads();
    for (int d = 1; d < 256; d <<= 1) {
        int u = (t >= d) ? tmp[t - d] : 0;
        __syncthreads();
        tmp[t] += u;
        __syncthreads();
    }
    if (i < N_NODES) localScan[i] = tmp[t] - v;  // exclusive
    if (t == 255) blockSums[blockIdx.x] = tmp[t];
}

__global__ __launch_bounds__(256) void scan2_kernel(const int* __restrict__ blockSums,
                                                    int* __restrict__ blockBase) {
    __shared__ int tmp[256];
    int t = threadIdx.x;
    int v = (t < SCAN_BLOCKS) ? blockSums[t] : 0;
    tmp[t] = v;
    __syncthreads();
    for (int d = 1; d < 256; d <<= 1) {
        int u = (t >= d) ? tmp[t - d] : 0;
        __syncthreads();
        tmp[t] += u;
        __syncthreads();
    }
    blockBase[t] = tmp[t] - v;  // exclusive
}

__global__ void scan3_kernel(const int* __restrict__ localScan,
                             const int* __restrict__ blockBase,
                             int* __restrict__ offs, int* __restrict__ fill) {
    int i = blockIdx.x * 256 + threadIdx.x;
    if (i < N_NODES) {
        int o = localScan[i] + blockBase[i >> 8];
        offs[i] = o;
        fill[i] = o;
    }
    if (i == 0) offs[N_NODES] = E_TOT;
}

__global__ void scatter_kernel(const int* __restrict__ ei, int* __restrict__ fill,
                               int* __restrict__ bucket) {
    int e = blockIdx.x * blockDim.x + threadIdx.x;
    if (e >= E_TOT) return;
    int s, d;
    if (e < N_EDGES) { s = ei[e]; d = ei[N_EDGES + e]; }
    else             { s = d = e - N_EDGES; }
    int pos = atomicAdd(&fill[d], 1);
    bucket[pos] = s;
}

// deterministic ordering: sort each node's bucket by src id.
// one WAVE per node; <=64 elements sorted in-register via bitonic network.
__global__ __launch_bounds__(256) void sort_kernel(const int* __restrict__ offs,
                                                   int* __restrict__ bucket) {
    int w = (blockIdx.x * blockDim.x + threadIdx.x) >> 6;
    int l = threadIdx.x & 63;
    if (w >= N_NODES) return;
    int a = offs[w];
    int deg = offs[w + 1] - a;
    if (deg <= 1) return;
    if (deg <= 64) {
        int v = (l < deg) ? bucket[a + l] : 0x7fffffff;
#pragma unroll
        for (int k = 2; k <= 64; k <<= 1) {
#pragma unroll
            for (int j = k >> 1; j >= 1; j >>= 1) {
                int u = __shfl_xor(v, j, 64);
                bool up    = ((l & k) == 0);
                bool lower = ((l & j) == 0);
                int mn = min(v, u), mx = max(v, u);
                v = (up == lower) ? mn : mx;
            }
        }
        if (l < deg) bucket[a + l] = v;
    } else if (l == 0) {
        // fallback (deg>64 essentially impossible for this graph, kept for correctness)
        for (int i = a + 1; i < a + deg; i++) {
            int key = bucket[i];
            int j = i - 1;
            while (j >= a && bucket[j] > key) { bucket[j + 1] = bucket[j]; j--; }
            bucket[j + 1] = key;
        }
    }
}

// ---------------- layer 1 GEMM: h1 = x @ W1, plus per-(node,head) attn dots ----------------
// thread = (head, 4 consecutive nodes); block covers 256 nodes.
__global__ __launch_bounds__(256) void gemm1_kernel(const float* __restrict__ x,
                                                    const float* __restrict__ W1,
                                                    const float* __restrict__ asrc1,
                                                    const float* __restrict__ adst1,
                                                    float* __restrict__ h1,
                                                    float* __restrict__ as1,
                                                    float* __restrict__ ad1) {
    // W layout: wlds[head*4104 + k*32 + j]  (head stride 4104 -> bank offset 8*head)
    __shared__ __align__(16) float wlds[4 * 4104];
    // x tile transposed: xs[kk*260 + row]  (row-stride 260 -> <=2-way conflicts)
    __shared__ __align__(16) float xs[32 * 260];

    const int tid = threadIdx.x;
    const int head = tid & 3;
    const int q = tid >> 2;              // 0..63  -> nodes base+q*4 .. +3
    const int base = blockIdx.x * NBLK;

    for (int idx = tid; idx < 128 * 128; idx += 256) {
        int k = idx >> 7, col = idx & 127;
        wlds[(col >> 5) * 4104 + k * 32 + (col & 31)] = W1[idx];
    }

    float acc[4][32];
#pragma unroll
    for (int i = 0; i < 4; i++)
#pragma unroll
        for (int j = 0; j < 32; j++) acc[i][j] = 0.f;

    for (int kt = 0; kt < 4; kt++) {
        __syncthreads(); // protects xs reuse (and W load on first iter)
#pragma unroll
        for (int it = 0; it < 8; it++) {
            int idx = tid + it * 256;
            int row = idx >> 3, c4 = idx & 7;
            int node = base + row;
            float4 v = make_float4(0.f, 0.f, 0.f, 0.f);
            if (node < N_NODES)
                v = *(const float4*)(x + (size_t)node * 128 + kt * 32 + c4 * 4);
            xs[(c4 * 4 + 0) * 260 + row] = v.x;
            xs[(c4 * 4 + 1) * 260 + row] = v.y;
            xs[(c4 * 4 + 2) * 260 + row] = v.z;
            xs[(c4 * 4 + 3) * 260 + row] = v.w;
        }
        __syncthreads();

        for (int kk = 0; kk < 32; kk++) {
            float4 xv = *(const float4*)(xs + kk * 260 + q * 4);
            const float* wb = wlds + head * 4104 + (kt * 32 + kk) * 32;
            float xvv[4] = {xv.x, xv.y, xv.z, xv.w};
#pragma unroll
            for (int j4 = 0; j4 < 8; j4++) {
                float4 wv = *(const float4*)(wb + j4 * 4);
                float wvv[4] = {wv.x, wv.y, wv.z, wv.w};
#pragma unroll
                for (int i = 0; i < 4; i++)
#pragma unroll
                    for (int c = 0; c < 4; c++)
                        acc[i][j4 * 4 + c] += xvv[i] * wvv[c];
            }
        }
    }

    // epilogue: write h1 and attention half-dots
#pragma unroll
    for (int i = 0; i < 4; i++) {
        int node = base + q * 4 + i;
        if (node >= N_NODES) continue;
#pragma unroll
        for (int j4 = 0; j4 < 8; j4++) {
            float4 hv = make_float4(acc[i][j4 * 4 + 0], acc[i][j4 * 4 + 1],
                                    acc[i][j4 * 4 + 2], acc[i][j4 * 4 + 3]);
            *(float4*)(h1 + (size_t)node * 128 + head * 32 + j4 * 4) = hv;
        }
        float sa = 0.f, da = 0.f;
#pragma unroll
        for (int j = 0; j < 32; j++) {
            float v = acc[i][j];
            sa += v * asrc1[head * 32 + j];
            da += v * adst1[head * 32 + j];
        }
        as1[node * 4 + head] = sa;
        ad1[node * 4 + head] = da;
    }
}

// ---------------- layer 1 aggregation (+bias, ELU, layer-2 projection) ----------------
// one wave per dst node; lane l owns channels 2l, 2l+1 (head = l>>4).
// softmax without max-subtract (logits bounded); denom tracked per-lane.
__global__ __launch_bounds__(256) void agg1_kernel(const float* __restrict__ h1,
                                                   const float* __restrict__ as1,
                                                   const float* __restrict__ ad1,
                                                   const int* __restrict__ offs,
                                                   const int* __restrict__ bucket,
                                                   const float* __restrict__ b1,
                                                   const float* __restrict__ W2,
                                                   float* __restrict__ x2,
                                                   float* __restrict__ h2s) {
    int w = threadIdx.x >> 6, l = threadIdx.x & 63;
    int node = blockIdx.x * 4 + w;
    if (node >= N_NODES) return;
    int head = l >> 4;
    float adh = ad1[node * 4 + head];
    int a = offs[node];
    int deg = offs[node + 1] - a;

    float sx = 0.f, ax = 0.f, ay = 0.f;
    for (int i = 0; i < deg; i++) {
        int s = bucket[a + i];
        float e = as1[s * 4 + head] + adh;
        e = (e > 0.f) ? e : 0.2f * e;
        float ex = __expf(e);
        float2 hv = ((const float2*)(h1 + (size_t)s * 128))[l];
        sx += ex;
        ax += ex * hv.x;
        ay += ex * hv.y;
    }
    float r = 1.f / (sx + 1e-16f);
    float2 bv = ((const float2*)b1)[l];
    float ox = ax * r + bv.x;
    float oy = ay * r + bv.y;
    // ELU
    float xx = (ox > 0.f) ? ox : (__expf(ox) - 1.f);
    float xy = (oy > 0.f) ? oy : (__expf(oy) - 1.f);
    ((float2*)(x2 + (size_t)node * 128))[l] = make_float2(xx, xy);
    // layer-2 linear: h2s[node] = elu(out1) . W2
    float2 wv = ((const float2*)W2)[l];
    float p = xx * wv.x + xy * wv.y;
#pragma unroll
    for (int o = 32; o > 0; o >>= 1) p += __shfl_xor(p, o, 64);
    if (l == 0) h2s[node] = p;
}

// ---------------- layer 2 aggregation ----------------
// one wave per dst node; lanes parallel over edges.
__global__ __launch_bounds__(256) void agg2_kernel(const float* __restrict__ h2s,
                                                   const int* __restrict__ offs,
                                                   const int* __restrict__ bucket,
                                                   const float* __restrict__ asrc2,
                                                   const float* __restrict__ adst2,
                                                   const float* __restrict__ b2,
                                                   float* __restrict__ out) {
    int w = threadIdx.x >> 6, l = threadIdx.x & 63;
    int node = blockIdx.x * 4 + w;
    if (node >= N_NODES) return;
    float asc = asrc2[0], adc = adst2[0], bias = b2[0];
    float adn = h2s[node] * adc;
    int a = offs[node], b = offs[node + 1];
    float sx = 0.f, sw = 0.f;
    for (int i = a + l; i < b; i += 64) {
        float hs = h2s[bucket[i]];
        float e = hs * asc + adn;
        e = (e > 0.f) ? e : 0.2f * e;
        float ex = __expf(e);
        sx += ex;
        sw += ex * hs;
    }
#pragma unroll
    for (int o = 32; o > 0; o >>= 1) {
        sx += __shfl_xor(sx, o, 64);
        sw += __shfl_xor(sw, o, 64);
    }
    if (l == 0) out[node] = sw / (sx + 1e-16f) + bias;
}

// ---------------- launch ----------------

extern "C" void kernel_launch(void* const* d_in, const int* in_sizes, int n_in,
                              void* d_out, int out_size, void* d_ws, size_t ws_size,
                              hipStream_t stream) {
    const float* x     = (const float*)d_in[0];
    const int*   ei    = (const int*)d_in[1];
    const float* W1    = (const float*)d_in[2];
    const float* asrc1 = (const float*)d_in[3];
    const float* adst1 = (const float*)d_in[4];
    const float* b1    = (const float*)d_in[5];
    const float* W2    = (const float*)d_in[6];
    const float* asrc2 = (const float*)d_in[7];
    const float* adst2 = (const float*)d_in[8];
    const float* b2    = (const float*)d_in[9];
    float* out = (float*)d_out;

    char* ws = (char*)d_ws;
    size_t o = 0;
    auto alloc = [&](size_t bytes) -> void* {
        void* p = ws + o;
        o += (bytes + 255) & ~(size_t)255;
        return p;
    };
    int* counts  = (int*)alloc((size_t)N_NODES * 4);
    int* offs    = (int*)alloc((size_t)(N_NODES + 1) * 4);
    int* fill    = (int*)alloc((size_t)N_NODES * 4);
    int* bucket  = (int*)alloc((size_t)E_TOT * 4);
    float* h1    = (float*)alloc((size_t)N_NODES * 128 * 4);
    float* as1   = (float*)alloc((size_t)N_NODES * 4 * 4);
    float* ad1   = (float*)alloc((size_t)N_NODES * 4 * 4);
    float* x2    = (float*)alloc((size_t)N_NODES * 128 * 4);
    float* h2s   = (float*)alloc((size_t)N_NODES * 4);
    int* localScan = (int*)alloc((size_t)N_NODES * 4);
    int* blockSums = (int*)alloc((size_t)SCAN_BLOCKS * 4);
    int* blockBase = (int*)alloc((size_t)256 * 4);

    hipMemsetAsync(counts, 0, (size_t)N_NODES * 4, stream);

    hist_kernel<<<(E_TOT + 255) / 256, 256, 0, stream>>>(ei, counts);
    scan1_kernel<<<SCAN_BLOCKS, 256, 0, stream>>>(counts, localScan, blockSums);
    scan2_kernel<<<1, 256, 0, stream>>>(blockSums, blockBase);
    scan3_kernel<<<SCAN_BLOCKS, 256, 0, stream>>>(localScan, blockBase, offs, fill);
    scatter_kernel<<<(E_TOT + 255) / 256, 256, 0, stream>>>(ei, fill, bucket);
    sort_kernel<<<(N_NODES * 64 + 255) / 256, 256, 0, stream>>>(offs, bucket);

    gemm1_kernel<<<(N_NODES + NBLK - 1) / NBLK, 256, 0, stream>>>(
        x, W1, asrc1, adst1, h1, as1, ad1);

    agg1_kernel<<<(N_NODES + 3) / 4, 256, 0, stream>>>(
        h1, as1, ad1, offs, bucket, b1, W2, x2, h2s);

    agg2_kernel<<<(N_NODES + 3) / 4, 256, 0, stream>>>(
        h2s, offs, bucket, asrc2, adst2, b2, out);
}

// Round 4
// 235.673 us; speedup vs baseline: 2.0201x; 1.2570x over previous
//
#include <hip/hip_runtime.h>
#include <hip/hip_bf16.h>
#include <hip/hip_fp16.h>

#define N_NODES 50000
#define N_EDGES 800000
#define E_TOT   850000   // + self loops
#define NBLK    256      // nodes per gemm block
#define SCAN_BLOCKS 196  // ceil(50000/256)

// ---------------- CSR build ----------------

__global__ void hist_kernel(const int* __restrict__ ei, int* __restrict__ counts) {
    int e = blockIdx.x * blockDim.x + threadIdx.x;
    if (e >= E_TOT) return;
    int d = (e < N_EDGES) ? ei[N_EDGES + e] : (e - N_EDGES);
    atomicAdd(&counts[d], 1);
}

// hierarchical exclusive scan: local 256-scan -> block-sum scan -> add base
__global__ __launch_bounds__(256) void scan1_kernel(const int* __restrict__ counts,
                                                    int* __restrict__ localScan,
                                                    int* __restrict__ blockSums) {
    __shared__ int tmp[256];
    int t = threadIdx.x, i = blockIdx.x * 256 + t;
    int v = (i < N_NODES) ? counts[i] : 0;
    tmp[t] = v;
    __syncthreads();
    for (int d = 1; d < 256; d <<= 1) {
        int u = (t >= d) ? tmp[t - d] : 0;
        __syncthreads();
        tmp[t] += u;
        __syncthreads();
    }
    if (i < N_NODES) localScan[i] = tmp[t] - v;  // exclusive
    if (t == 255) blockSums[blockIdx.x] = tmp[t];
}

__global__ __launch_bounds__(256) void scan2_kernel(const int* __restrict__ blockSums,
                                                    int* __restrict__ blockBase) {
    __shared__ int tmp[256];
    int t = threadIdx.x;
    int v = (t < SCAN_BLOCKS) ? blockSums[t] : 0;
    tmp[t] = v;
    __syncthreads();
    for (int d = 1; d < 256; d <<= 1) {
        int u = (t >= d) ? tmp[t - d] : 0;
        __syncthreads();
        tmp[t] += u;
        __syncthreads();
    }
    blockBase[t] = tmp[t] - v;  // exclusive
}

__global__ void scan3_kernel(const int* __restrict__ localScan,
                             const int* __restrict__ blockBase,
                             int* __restrict__ offs, int* __restrict__ fill) {
    int i = blockIdx.x * 256 + threadIdx.x;
    if (i < N_NODES) {
        int o = localScan[i] + blockBase[i >> 8];
        offs[i] = o;
        fill[i] = o;
    }
    if (i == 0) offs[N_NODES] = E_TOT;
}

__global__ void scatter_kernel(const int* __restrict__ ei, int* __restrict__ fill,
                               int* __restrict__ bucket) {
    int e = blockIdx.x * blockDim.x + threadIdx.x;
    if (e >= E_TOT) return;
    int s, d;
    if (e < N_EDGES) { s = ei[e]; d = ei[N_EDGES + e]; }
    else             { s = d = e - N_EDGES; }
    int pos = atomicAdd(&fill[d], 1);
    bucket[pos] = s;
}

// deterministic ordering: sort each node's bucket by src id.
// one WAVE per node; <=64 elements sorted in-register via bitonic network.
__global__ __launch_bounds__(256) void sort_kernel(const int* __restrict__ offs,
                                                   int* __restrict__ bucket) {
    int w = (blockIdx.x * blockDim.x + threadIdx.x) >> 6;
    int l = threadIdx.x & 63;
    if (w >= N_NODES) return;
    int a = offs[w];
    int deg = offs[w + 1] - a;
    if (deg <= 1) return;
    if (deg <= 64) {
        int v = (l < deg) ? bucket[a + l] : 0x7fffffff;
#pragma unroll
        for (int k = 2; k <= 64; k <<= 1) {
#pragma unroll
            for (int j = k >> 1; j >= 1; j >>= 1) {
                int u = __shfl_xor(v, j, 64);
                bool up    = ((l & k) == 0);
                bool lower = ((l & j) == 0);
                int mn = min(v, u), mx = max(v, u);
                v = (up == lower) ? mn : mx;
            }
        }
        if (l < deg) bucket[a + l] = v;
    } else if (l == 0) {
        // fallback (deg>64 essentially impossible for this graph, kept for correctness)
        for (int i = a + 1; i < a + deg; i++) {
            int key = bucket[i];
            int j = i - 1;
            while (j >= a && bucket[j] > key) { bucket[j + 1] = bucket[j]; j--; }
            bucket[j + 1] = key;
        }
    }
}

// ---------------- layer 1 GEMM: h1 = x @ W1 (fp16 out), plus per-(node,head) attn dots ----------------
// thread = (head, 4 consecutive nodes); block covers 256 nodes.
__global__ __launch_bounds__(256) void gemm1_kernel(const float* __restrict__ x,
                                                    const float* __restrict__ W1,
                                                    const float* __restrict__ asrc1,
                                                    const float* __restrict__ adst1,
                                                    __half* __restrict__ h1,
                                                    float* __restrict__ as1,
                                                    float* __restrict__ ad1) {
    // W layout: wlds[head*4104 + k*32 + j]  (head stride 4104 -> bank offset 8*head)
    __shared__ __align__(16) float wlds[4 * 4104];
    // x tile transposed: xs[kk*260 + row]  (row-stride 260 -> <=2-way conflicts)
    __shared__ __align__(16) float xs[32 * 260];

    const int tid = threadIdx.x;
    const int head = tid & 3;
    const int q = tid >> 2;              // 0..63  -> nodes base+q*4 .. +3
    const int base = blockIdx.x * NBLK;

    for (int idx = tid; idx < 128 * 128; idx += 256) {
        int k = idx >> 7, col = idx & 127;
        wlds[(col >> 5) * 4104 + k * 32 + (col & 31)] = W1[idx];
    }

    float acc[4][32];
#pragma unroll
    for (int i = 0; i < 4; i++)
#pragma unroll
        for (int j = 0; j < 32; j++) acc[i][j] = 0.f;

    for (int kt = 0; kt < 4; kt++) {
        __syncthreads(); // protects xs reuse (and W load on first iter)
#pragma unroll
        for (int it = 0; it < 8; it++) {
            int idx = tid + it * 256;
            int row = idx >> 3, c4 = idx & 7;
            int node = base + row;
            float4 v = make_float4(0.f, 0.f, 0.f, 0.f);
            if (node < N_NODES)
                v = *(const float4*)(x + (size_t)node * 128 + kt * 32 + c4 * 4);
            xs[(c4 * 4 + 0) * 260 + row] = v.x;
            xs[(c4 * 4 + 1) * 260 + row] = v.y;
            xs[(c4 * 4 + 2) * 260 + row] = v.z;
            xs[(c4 * 4 + 3) * 260 + row] = v.w;
        }
        __syncthreads();

        for (int kk = 0; kk < 32; kk++) {
            float4 xv = *(const float4*)(xs + kk * 260 + q * 4);
            const float* wb = wlds + head * 4104 + (kt * 32 + kk) * 32;
            float xvv[4] = {xv.x, xv.y, xv.z, xv.w};
#pragma unroll
            for (int j4 = 0; j4 < 8; j4++) {
                float4 wv = *(const float4*)(wb + j4 * 4);
                float wvv[4] = {wv.x, wv.y, wv.z, wv.w};
#pragma unroll
                for (int i = 0; i < 4; i++)
#pragma unroll
                    for (int c = 0; c < 4; c++)
                        acc[i][j4 * 4 + c] += xvv[i] * wvv[c];
            }
        }
    }

    // epilogue: write h1 (fp16) and attention half-dots (fp32)
#pragma unroll
    for (int i = 0; i < 4; i++) {
        int node = base + q * 4 + i;
        if (node >= N_NODES) continue;
        __half2* hp = (__half2*)(h1 + (size_t)node * 128 + head * 32);
#pragma unroll
        for (int j4 = 0; j4 < 8; j4++) {
            hp[j4 * 2 + 0] = __floats2half2_rn(acc[i][j4 * 4 + 0], acc[i][j4 * 4 + 1]);
            hp[j4 * 2 + 1] = __floats2half2_rn(acc[i][j4 * 4 + 2], acc[i][j4 * 4 + 3]);
        }
        float sa = 0.f, da = 0.f;
#pragma unroll
        for (int j = 0; j < 32; j++) {
            float v = acc[i][j];
            sa += v * asrc1[head * 32 + j];
            da += v * adst1[head * 32 + j];
        }
        as1[node * 4 + head] = sa;
        ad1[node * 4 + head] = da;
    }
}

// ---------------- layer 1 aggregation (+bias, ELU, layer-2 projection) ----------------
// one wave per dst node; lane l owns channels 2l, 2l+1 (head = l>>4).
// softmax without max-subtract (logits bounded); denom tracked per-lane.
// 4-way unrolled edge loop: 4 independent gather chains in flight.
__global__ __launch_bounds__(256) void agg1_kernel(const __half* __restrict__ h1,
                                                   const float* __restrict__ as1,
                                                   const float* __restrict__ ad1,
                                                   const int* __restrict__ offs,
                                                   const int* __restrict__ bucket,
                                                   const float* __restrict__ b1,
                                                   const float* __restrict__ W2,
                                                   float* __restrict__ h2s) {
    int w = threadIdx.x >> 6, l = threadIdx.x & 63;
    int node = blockIdx.x * 4 + w;
    if (node >= N_NODES) return;
    int head = l >> 4;
    float adh = ad1[node * 4 + head];
    int a = offs[node];
    int deg = offs[node + 1] - a;

    float sx = 0.f, ax = 0.f, ay = 0.f;
    int i = 0;
    for (; i + 4 <= deg; i += 4) {
        int s0 = bucket[a + i + 0];
        int s1 = bucket[a + i + 1];
        int s2 = bucket[a + i + 2];
        int s3 = bucket[a + i + 3];
        float e0 = as1[s0 * 4 + head] + adh;
        float e1 = as1[s1 * 4 + head] + adh;
        float e2 = as1[s2 * 4 + head] + adh;
        float e3 = as1[s3 * 4 + head] + adh;
        __half2 v0 = ((const __half2*)(h1 + (size_t)s0 * 128))[l];
        __half2 v1 = ((const __half2*)(h1 + (size_t)s1 * 128))[l];
        __half2 v2 = ((const __half2*)(h1 + (size_t)s2 * 128))[l];
        __half2 v3 = ((const __half2*)(h1 + (size_t)s3 * 128))[l];
        e0 = (e0 > 0.f) ? e0 : 0.2f * e0;
        e1 = (e1 > 0.f) ? e1 : 0.2f * e1;
        e2 = (e2 > 0.f) ? e2 : 0.2f * e2;
        e3 = (e3 > 0.f) ? e3 : 0.2f * e3;
        float x0 = __expf(e0), x1 = __expf(e1), x2e = __expf(e2), x3 = __expf(e3);
        float2 f0 = __half22float2(v0);
        float2 f1 = __half22float2(v1);
        float2 f2 = __half22float2(v2);
        float2 f3 = __half22float2(v3);
        sx += (x0 + x1) + (x2e + x3);
        ax += x0 * f0.x + x1 * f1.x + x2e * f2.x + x3 * f3.x;
        ay += x0 * f0.y + x1 * f1.y + x2e * f2.y + x3 * f3.y;
    }
    for (; i < deg; i++) {
        int s = bucket[a + i];
        float e = as1[s * 4 + head] + adh;
        e = (e > 0.f) ? e : 0.2f * e;
        float ex = __expf(e);
        float2 f = __half22float2(((const __half2*)(h1 + (size_t)s * 128))[l]);
        sx += ex;
        ax += ex * f.x;
        ay += ex * f.y;
    }
    float r = 1.f / (sx + 1e-16f);
    float2 bv = ((const float2*)b1)[l];
    float ox = ax * r + bv.x;
    float oy = ay * r + bv.y;
    // ELU
    float xx = (ox > 0.f) ? ox : (__expf(ox) - 1.f);
    float xy = (oy > 0.f) ? oy : (__expf(oy) - 1.f);
    // layer-2 linear: h2s[node] = elu(out1) . W2   (x2 itself is never consumed)
    float2 wv = ((const float2*)W2)[l];
    float p = xx * wv.x + xy * wv.y;
#pragma unroll
    for (int o = 32; o > 0; o >>= 1) p += __shfl_xor(p, o, 64);
    if (l == 0) h2s[node] = p;
}

// ---------------- layer 2 aggregation ----------------
// one wave per dst node; lanes parallel over edges.
__global__ __launch_bounds__(256) void agg2_kernel(const float* __restrict__ h2s,
                                                   const int* __restrict__ offs,
                                                   const int* __restrict__ bucket,
                                                   const float* __restrict__ asrc2,
                                                   const float* __restrict__ adst2,
                                                   const float* __restrict__ b2,
                                                   float* __restrict__ out) {
    int w = threadIdx.x >> 6, l = threadIdx.x & 63;
    int node = blockIdx.x * 4 + w;
    if (node >= N_NODES) return;
    float asc = asrc2[0], adc = adst2[0], bias = b2[0];
    float adn = h2s[node] * adc;
    int a = offs[node], b = offs[node + 1];
    float sx = 0.f, sw = 0.f;
    for (int i = a + l; i < b; i += 64) {
        float hs = h2s[bucket[i]];
        float e = hs * asc + adn;
        e = (e > 0.f) ? e : 0.2f * e;
        float ex = __expf(e);
        sx += ex;
        sw += ex * hs;
    }
#pragma unroll
    for (int o = 32; o > 0; o >>= 1) {
        sx += __shfl_xor(sx, o, 64);
        sw += __shfl_xor(sw, o, 64);
    }
    if (l == 0) out[node] = sw / (sx + 1e-16f) + bias;
}

// ---------------- launch ----------------

extern "C" void kernel_launch(void* const* d_in, const int* in_sizes, int n_in,
                              void* d_out, int out_size, void* d_ws, size_t ws_size,
                              hipStream_t stream) {
    const float* x     = (const float*)d_in[0];
    const int*   ei    = (const int*)d_in[1];
    const float* W1    = (const float*)d_in[2];
    const float* asrc1 = (const float*)d_in[3];
    const float* adst1 = (const float*)d_in[4];
    const float* b1    = (const float*)d_in[5];
    const float* W2    = (const float*)d_in[6];
    const float* asrc2 = (const float*)d_in[7];
    const float* adst2 = (const float*)d_in[8];
    const float* b2    = (const float*)d_in[9];
    float* out = (float*)d_out;

    char* ws = (char*)d_ws;
    size_t o = 0;
    auto alloc = [&](size_t bytes) -> void* {
        void* p = ws + o;
        o += (bytes + 255) & ~(size_t)255;
        return p;
    };
    int* counts  = (int*)alloc((size_t)N_NODES * 4);
    int* offs    = (int*)alloc((size_t)(N_NODES + 1) * 4);
    int* fill    = (int*)alloc((size_t)N_NODES * 4);
    int* bucket  = (int*)alloc((size_t)E_TOT * 4);
    __half* h1   = (__half*)alloc((size_t)N_NODES * 128 * 2);
    float* as1   = (float*)alloc((size_t)N_NODES * 4 * 4);
    float* ad1   = (float*)alloc((size_t)N_NODES * 4 * 4);
    float* h2s   = (float*)alloc((size_t)N_NODES * 4);
    int* localScan = (int*)alloc((size_t)N_NODES * 4);
    int* blockSums = (int*)alloc((size_t)SCAN_BLOCKS * 4);
    int* blockBase = (int*)alloc((size_t)256 * 4);

    hipMemsetAsync(counts, 0, (size_t)N_NODES * 4, stream);

    hist_kernel<<<(E_TOT + 255) / 256, 256, 0, stream>>>(ei, counts);
    scan1_kernel<<<SCAN_BLOCKS, 256, 0, stream>>>(counts, localScan, blockSums);
    scan2_kernel<<<1, 256, 0, stream>>>(blockSums, blockBase);
    scan3_kernel<<<SCAN_BLOCKS, 256, 0, stream>>>(localScan, blockBase, offs, fill);
    scatter_kernel<<<(E_TOT + 255) / 256, 256, 0, stream>>>(ei, fill, bucket);
    sort_kernel<<<(N_NODES * 64 + 255) / 256, 256, 0, stream>>>(offs, bucket);

    gemm1_kernel<<<(N_NODES + NBLK - 1) / NBLK, 256, 0, stream>>>(
        x, W1, asrc1, adst1, h1, as1, ad1);

    agg1_kernel<<<(N_NODES + 3) / 4, 256, 0, stream>>>(
        h1, as1, ad1, offs, bucket, b1, W2, h2s);

    agg2_kernel<<<(N_NODES + 3) / 4, 256, 0, stream>>>(
        h2s, offs, bucket, asrc2, adst2, b2, out);
}